// Round 2
// baseline (111.025 us; speedup 1.0000x reference)
//
#include <hip/hip_runtime.h>

constexpr int BATCH = 131072;
constexpr int FEAT  = 384;
constexpr int F4    = FEAT / 4;          // 96 float4 per row
constexpr float ALPHA = 0.2f;
constexpr int NBLOCKS = 2048;
constexpr int BLOCK   = 256;
constexpr int WAVES_PER_BLOCK = BLOCK / 64;

__device__ __forceinline__ float wdot(const float4& w, const float4& a,
                                      const float4& p, const float4& n) {
    float dp, dn, r;
    dp = a.x - p.x; dn = a.x - n.x; r  = w.x * (dp * dp - dn * dn);
    dp = a.y - p.y; dn = a.y - n.y; r += w.y * (dp * dp - dn * dn);
    dp = a.z - p.z; dn = a.z - n.z; r += w.z * (dp * dp - dn * dn);
    dp = a.w - p.w; dn = a.w - n.w; r += w.w * (dp * dp - dn * dn);
    return r;
}

__device__ __forceinline__ float wave_sum(float v) {
    // 64-lane butterfly: all lanes end with the full sum
    #pragma unroll
    for (int m = 1; m < 64; m <<= 1) v += __shfl_xor(v, m, 64);
    return v;
}

__global__ __launch_bounds__(BLOCK) void triplet_partial(
    const float4* __restrict__ A, const float4* __restrict__ P,
    const float4* __restrict__ N, const float* __restrict__ W,
    float* __restrict__ partial)
{
    const int lane = threadIdx.x & 63;
    const int wave = threadIdx.x >> 6;
    const int gw    = blockIdx.x * WAVES_PER_BLOCK + wave;
    const int nwave = gridDim.x * WAVES_PER_BLOCK;

    // Per-lane exp(W) fragments. Over a 2-row (192-float4) tile, lane L's
    // three float4 slots are tile-offsets {L, 64+L, 128+L}; mapped to the
    // 96-float4 row period those are w-indices {L, L<32?64+L:L-32, 32+L}.
    const float4* W4 = reinterpret_cast<const float4*>(W);
    float4 w0 = W4[lane];
    float4 w1 = W4[(lane < 32) ? (64 + lane) : (lane - 32)];
    float4 w2 = W4[32 + lane];
    w0.x = expf(w0.x); w0.y = expf(w0.y); w0.z = expf(w0.z); w0.w = expf(w0.w);
    w1.x = expf(w1.x); w1.y = expf(w1.y); w1.z = expf(w1.z); w1.w = expf(w1.w);
    w2.x = expf(w2.x); w2.y = expf(w2.y); w2.z = expf(w2.z); w2.w = expf(w2.w);

    float acc = 0.f;
    const int nrp = BATCH / 2;   // row pairs
    for (int rp = gw; rp < nrp; rp += nwave) {
        const int base = rp * (2 * F4);
        float s0, s1;
        {   // slot 0: all lanes row 0
            const int i = base + lane;
            s0 = wdot(w0, A[i], P[i], N[i]);
        }
        {   // slot 1: lanes 0-31 row 0, lanes 32-63 row 1
            const int i = base + 64 + lane;
            const float v = wdot(w1, A[i], P[i], N[i]);
            if (lane < 32) s0 += v; else s1 = v; // s1 init here for lanes>=32
            if (lane < 32) s1 = 0.f;
        }
        {   // slot 2: all lanes row 1
            const int i = base + 128 + lane;
            s1 += wdot(w2, A[i], P[i], N[i]);
        }
        s0 = wave_sum(s0);
        s1 = wave_sum(s1);
        acc += fmaxf(s0 + ALPHA, 0.f) + fmaxf(s1 + ALPHA, 0.f);
    }

    __shared__ float lds[WAVES_PER_BLOCK];
    if (lane == 0) lds[wave] = acc;
    __syncthreads();
    if (threadIdx.x == 0) {
        float b = 0.f;
        #pragma unroll
        for (int i = 0; i < WAVES_PER_BLOCK; ++i) b += lds[i];
        partial[blockIdx.x] = b;
    }
}

__global__ __launch_bounds__(256) void triplet_finish(
    const float* __restrict__ partial, float* __restrict__ out)
{
    __shared__ float lds[256];
    float s = 0.f;
    for (int i = threadIdx.x; i < NBLOCKS; i += 256) s += partial[i];
    lds[threadIdx.x] = s;
    __syncthreads();
    for (int ofs = 128; ofs > 0; ofs >>= 1) {
        if (threadIdx.x < ofs) lds[threadIdx.x] += lds[threadIdx.x + ofs];
        __syncthreads();
    }
    if (threadIdx.x == 0) out[0] = lds[0] / (float)BATCH;
}

extern "C" void kernel_launch(void* const* d_in, const int* in_sizes, int n_in,
                              void* d_out, int out_size, void* d_ws, size_t ws_size,
                              hipStream_t stream) {
    const float4* A = (const float4*)d_in[0];
    const float4* P = (const float4*)d_in[1];
    const float4* N = (const float4*)d_in[2];
    const float*  W = (const float*)d_in[3];
    float* partial = (float*)d_ws;   // NBLOCKS floats, fully written each call
    float* out = (float*)d_out;

    triplet_partial<<<NBLOCKS, BLOCK, 0, stream>>>(A, P, N, W, partial);
    triplet_finish<<<1, 256, 0, stream>>>(partial, out);
}

// Round 3
// 109.052 us; speedup vs baseline: 1.0181x; 1.0181x over previous
//
#include <hip/hip_runtime.h>

constexpr int BATCH = 131072;
constexpr int FEAT  = 384;
constexpr int F4    = FEAT / 4;          // 96 float4 per row
constexpr float ALPHA = 0.2f;
constexpr int NBLOCKS = 2048;
constexpr int BLOCK   = 256;
constexpr int WAVES_PER_BLOCK = BLOCK / 64;

__device__ __forceinline__ float wdot(const float4& w, const float4& a,
                                      const float4& p, const float4& n) {
    float dp, dn, r;
    dp = a.x - p.x; dn = a.x - n.x; r  = w.x * (dp * dp - dn * dn);
    dp = a.y - p.y; dn = a.y - n.y; r += w.y * (dp * dp - dn * dn);
    dp = a.z - p.z; dn = a.z - n.z; r += w.z * (dp * dp - dn * dn);
    dp = a.w - p.w; dn = a.w - n.w; r += w.w * (dp * dp - dn * dn);
    return r;
}

// 4-row tile per wave per iteration: 384 float4 = 6 slots of 64 lanes.
// Slot k covers tile float4-offsets [64k, 64k+64); row r covers [96r, 96r+96).
//   row0 = slot0(all) + slot1(lanes<32)     row1 = slot1(lanes>=32) + slot2(all)
//   row2 = slot3(all) + slot4(lanes<32)     row3 = slot4(lanes>=32) + slot5(all)
// W4 index for slot k, lane L: (64k + L) mod 96 -> period-3 pattern {w0,w1,w2}.
__global__ __launch_bounds__(BLOCK) void triplet_partial(
    const float4* __restrict__ A, const float4* __restrict__ P,
    const float4* __restrict__ N, const float* __restrict__ W,
    float* __restrict__ partial)
{
    const int lane = threadIdx.x & 63;
    const int wave = threadIdx.x >> 6;
    const int gw    = blockIdx.x * WAVES_PER_BLOCK + wave;
    const int nwave = NBLOCKS * WAVES_PER_BLOCK;

    const float4* W4 = reinterpret_cast<const float4*>(W);
    float4 w[3];
    w[0] = W4[lane];
    w[1] = W4[(lane < 32) ? (64 + lane) : (lane - 32)];
    w[2] = W4[32 + lane];
    #pragma unroll
    for (int k = 0; k < 3; ++k) {
        w[k].x = expf(w[k].x); w[k].y = expf(w[k].y);
        w[k].z = expf(w[k].z); w[k].w = expf(w[k].w);
    }

    const bool lo = (lane < 32);
    float acc = 0.f;
    const int ngrp = BATCH / 4;               // 32768 four-row groups
    for (int g = gw; g < ngrp; g += nwave) {  // exactly 4 iterations/wave
        const int base = g * (4 * F4) + lane;

        // Issue all 18 independent float4 loads up front (72 data VGPRs).
        float4 av[6], pv[6], nv[6];
        #pragma unroll
        for (int k = 0; k < 6; ++k) av[k] = A[base + 64 * k];
        #pragma unroll
        for (int k = 0; k < 6; ++k) pv[k] = P[base + 64 * k];
        #pragma unroll
        for (int k = 0; k < 6; ++k) nv[k] = N[base + 64 * k];

        float v[6];
        #pragma unroll
        for (int k = 0; k < 6; ++k) v[k] = wdot(w[k % 3], av[k], pv[k], nv[k]);

        float x0 = v[0] + (lo ? v[1] : 0.f);
        float x1 = v[2] + (lo ? 0.f : v[1]);
        float x2 = v[3] + (lo ? v[4] : 0.f);
        float x3 = v[5] + (lo ? 0.f : v[4]);

        // 4 independent 64-lane butterflies (ILP 4)
        #pragma unroll
        for (int m = 1; m < 64; m <<= 1) {
            x0 += __shfl_xor(x0, m, 64);
            x1 += __shfl_xor(x1, m, 64);
            x2 += __shfl_xor(x2, m, 64);
            x3 += __shfl_xor(x3, m, 64);
        }
        acc += fmaxf(x0 + ALPHA, 0.f) + fmaxf(x1 + ALPHA, 0.f)
             + fmaxf(x2 + ALPHA, 0.f) + fmaxf(x3 + ALPHA, 0.f);
    }

    __shared__ float lds[WAVES_PER_BLOCK];
    if (lane == 0) lds[wave] = acc;
    __syncthreads();
    if (threadIdx.x == 0) {
        float b = 0.f;
        #pragma unroll
        for (int i = 0; i < WAVES_PER_BLOCK; ++i) b += lds[i];
        partial[blockIdx.x] = b;
    }
}

__global__ __launch_bounds__(256) void triplet_finish(
    const float* __restrict__ partial, float* __restrict__ out)
{
    __shared__ float lds[256];
    float s = 0.f;
    for (int i = threadIdx.x; i < NBLOCKS; i += 256) s += partial[i];
    lds[threadIdx.x] = s;
    __syncthreads();
    for (int ofs = 128; ofs > 0; ofs >>= 1) {
        if (threadIdx.x < ofs) lds[threadIdx.x] += lds[threadIdx.x + ofs];
        __syncthreads();
    }
    if (threadIdx.x == 0) out[0] = lds[0] / (float)BATCH;
}

extern "C" void kernel_launch(void* const* d_in, const int* in_sizes, int n_in,
                              void* d_out, int out_size, void* d_ws, size_t ws_size,
                              hipStream_t stream) {
    const float4* A = (const float4*)d_in[0];
    const float4* P = (const float4*)d_in[1];
    const float4* N = (const float4*)d_in[2];
    const float*  W = (const float*)d_in[3];
    float* partial = (float*)d_ws;   // NBLOCKS floats, fully written each call
    float* out = (float*)d_out;

    triplet_partial<<<NBLOCKS, BLOCK, 0, stream>>>(A, P, N, W, partial);
    triplet_finish<<<1, 256, 0, stream>>>(partial, out);
}

// Round 4
// 106.712 us; speedup vs baseline: 1.0404x; 1.0219x over previous
//
#include <hip/hip_runtime.h>

#define AS1 __attribute__((address_space(1)))
#define AS3 __attribute__((address_space(3)))

constexpr int BATCH = 131072;
constexpr int FEAT  = 384;
constexpr int F4    = FEAT / 4;            // 96 float4 per row
constexpr float ALPHA = 0.2f;
constexpr int BLOCK   = 256;               // 4 waves
constexpr int NBLOCKS = 512;               // 2 blocks/CU, all co-resident
constexpr int ROWS_PER_TILE = 8;           // 2 rows per wave
constexpr int TILE_F4 = ROWS_PER_TILE * F4;      // 768 float4 = 12 KB/array
constexpr int NTILES  = BATCH / ROWS_PER_TILE;   // 16384
constexpr int TILES_PER_BLOCK = NTILES / NBLOCKS; // 32, exact

__device__ __forceinline__ float wdot(const float4& w, const float4& a,
                                      const float4& p, const float4& n) {
    float dp, dn, r;
    dp = a.x - p.x; dn = a.x - n.x; r  = w.x * (dp * dp - dn * dn);
    dp = a.y - p.y; dn = a.y - n.y; r += w.y * (dp * dp - dn * dn);
    dp = a.z - p.z; dn = a.z - n.z; r += w.z * (dp * dp - dn * dn);
    dp = a.w - p.w; dn = a.w - n.w; r += w.w * (dp * dp - dn * dn);
    return r;
}

// Stage one 8-row tile of A/P/N into LDS. 12 chunks of 1 KB per array;
// wave w issues chunks {w, w+4, w+8}: 9 global_load_lds per wave per tile.
// LDS dest is wave-uniform base; HW writes lane L at base + 16*L, matching
// the per-lane global address gX + off + lane (linear layout, no swizzle).
__device__ __forceinline__ void issue_tile(int wave, int lane,
    const float4* __restrict__ gA, const float4* __restrict__ gP,
    const float4* __restrict__ gN,
    float4* bA, float4* bP, float4* bN)
{
    #pragma unroll
    for (int j = 0; j < 3; ++j) {
        const int off = 64 * (wave + 4 * j);
        __builtin_amdgcn_global_load_lds((const AS1 void*)(gA + off + lane),
                                         (AS3 void*)(bA + off), 16, 0, 0);
        __builtin_amdgcn_global_load_lds((const AS1 void*)(gP + off + lane),
                                         (AS3 void*)(bP + off), 16, 0, 0);
        __builtin_amdgcn_global_load_lds((const AS1 void*)(gN + off + lane),
                                         (AS3 void*)(bN + off), 16, 0, 0);
    }
}

__global__ __launch_bounds__(BLOCK) void triplet_partial(
    const float4* __restrict__ A, const float4* __restrict__ P,
    const float4* __restrict__ N, const float* __restrict__ W,
    float* __restrict__ partial)
{
    __shared__ float4 sA[2][TILE_F4];
    __shared__ float4 sP[2][TILE_F4];
    __shared__ float4 sN[2][TILE_F4];
    __shared__ float wpart[BLOCK / 64];

    const int lane = threadIdx.x & 63;
    const int wave = threadIdx.x >> 6;
    const int bid  = blockIdx.x;

    // exp(W) fragments; wave-invariant mapping: this wave's 2 rows span
    // tile-float4 [192*wave, 192*wave+192); slot s offset (64s+L) mod 96.
    const float4* W4 = reinterpret_cast<const float4*>(W);
    float4 w0 = W4[lane];
    float4 w1 = W4[(lane < 32) ? (64 + lane) : (lane - 32)];
    float4 w2 = W4[32 + lane];
    w0.x = expf(w0.x); w0.y = expf(w0.y); w0.z = expf(w0.z); w0.w = expf(w0.w);
    w1.x = expf(w1.x); w1.y = expf(w1.y); w1.z = expf(w1.z); w1.w = expf(w1.w);
    w2.x = expf(w2.x); w2.y = expf(w2.y); w2.z = expf(w2.z); w2.w = expf(w2.w);
    const bool lo = (lane < 32);
    const int wbase = 192 * wave;

    float acc = 0.f;

    // Block b streams tiles {b, b+512, b+1024, ...}: prologue + DEPTH-2 loop.
    issue_tile(wave, lane, A + (size_t)bid * TILE_F4, P + (size_t)bid * TILE_F4,
               N + (size_t)bid * TILE_F4, sA[0], sP[0], sN[0]);

    for (int i = 0; i < TILES_PER_BLOCK; ++i) {
        if (i + 1 < TILES_PER_BLOCK) {
            const size_t g = (size_t)(bid + NBLOCKS * (i + 1)) * TILE_F4;
            issue_tile(wave, lane, A + g, P + g, N + g,
                       sA[(i + 1) & 1], sP[(i + 1) & 1], sN[(i + 1) & 1]);
            // tile i's 9 loads done; tile i+1's 9 stay in flight
            asm volatile("s_waitcnt vmcnt(9)" ::: "memory");
        } else {
            asm volatile("s_waitcnt vmcnt(0)" ::: "memory");
        }
        __builtin_amdgcn_s_barrier();        // all waves' tile-i data landed
        __builtin_amdgcn_sched_barrier(0);

        const int b = i & 1;
        const float4 a0 = sA[b][wbase + lane];
        const float4 p0 = sP[b][wbase + lane];
        const float4 n0 = sN[b][wbase + lane];
        const float4 a1 = sA[b][wbase + 64 + lane];
        const float4 p1 = sP[b][wbase + 64 + lane];
        const float4 n1 = sN[b][wbase + 64 + lane];
        const float4 a2 = sA[b][wbase + 128 + lane];
        const float4 p2 = sP[b][wbase + 128 + lane];
        const float4 n2 = sN[b][wbase + 128 + lane];

        const float v0 = wdot(w0, a0, p0, n0);
        const float v1 = wdot(w1, a1, p1, n1);
        const float v2 = wdot(w2, a2, p2, n2);

        float x0 = v0 + (lo ? v1 : 0.f);     // row 2*wave
        float x1 = v2 + (lo ? 0.f : v1);     // row 2*wave+1
        #pragma unroll
        for (int m = 1; m < 64; m <<= 1) {
            x0 += __shfl_xor(x0, m, 64);
            x1 += __shfl_xor(x1, m, 64);
        }
        acc += fmaxf(x0 + ALPHA, 0.f) + fmaxf(x1 + ALPHA, 0.f);

        __builtin_amdgcn_s_barrier();        // reads done before buffer reuse
        __builtin_amdgcn_sched_barrier(0);
    }

    if (lane == 0) wpart[wave] = acc;
    __syncthreads();
    if (threadIdx.x == 0)
        partial[bid] = wpart[0] + wpart[1] + wpart[2] + wpart[3];
}

__global__ __launch_bounds__(256) void triplet_finish(
    const float* __restrict__ partial, float* __restrict__ out)
{
    __shared__ float lds[256];
    float s = 0.f;
    for (int i = threadIdx.x; i < NBLOCKS; i += 256) s += partial[i];
    lds[threadIdx.x] = s;
    __syncthreads();
    for (int ofs = 128; ofs > 0; ofs >>= 1) {
        if (threadIdx.x < ofs) lds[threadIdx.x] += lds[threadIdx.x + ofs];
        __syncthreads();
    }
    if (threadIdx.x == 0) out[0] = lds[0] / (float)BATCH;
}

extern "C" void kernel_launch(void* const* d_in, const int* in_sizes, int n_in,
                              void* d_out, int out_size, void* d_ws, size_t ws_size,
                              hipStream_t stream) {
    const float4* A = (const float4*)d_in[0];
    const float4* P = (const float4*)d_in[1];
    const float4* N = (const float4*)d_in[2];
    const float*  W = (const float*)d_in[3];
    float* partial = (float*)d_ws;   // NBLOCKS floats, fully written each call
    float* out = (float*)d_out;

    triplet_partial<<<NBLOCKS, BLOCK, 0, stream>>>(A, P, N, W, partial);
    triplet_finish<<<1, 256, 0, stream>>>(partial, out);
}

// Round 5
// 105.186 us; speedup vs baseline: 1.0555x; 1.0145x over previous
//
#include <hip/hip_runtime.h>

#define AS1 __attribute__((address_space(1)))
#define AS3 __attribute__((address_space(3)))

constexpr int BATCH = 131072;
constexpr int FEAT  = 384;
constexpr int F4    = FEAT / 4;            // 96 float4 per row
constexpr float ALPHA = 0.2f;
constexpr int BLOCK   = 256;               // 4 waves
constexpr int NBLOCKS = 512;               // 2 blocks/CU co-resident
constexpr int ROWS_PER_TILE = 8;           // 2 rows per wave
constexpr int TILE_F4 = ROWS_PER_TILE * F4;       // 768 float4 = 12 KB/array
constexpr int NTILES  = BATCH / ROWS_PER_TILE;    // 16384
constexpr int TILES_PER_BLOCK = NTILES / NBLOCKS; // 32, exact

__device__ __forceinline__ float wdot(const float4& w, const float4& a,
                                      const float4& p, const float4& n) {
    float dp, dn, r;
    dp = a.x - p.x; dn = a.x - n.x; r  = w.x * (dp * dp - dn * dn);
    dp = a.y - p.y; dn = a.y - n.y; r += w.y * (dp * dp - dn * dn);
    dp = a.z - p.z; dn = a.z - n.z; r += w.z * (dp * dp - dn * dn);
    dp = a.w - p.w; dn = a.w - n.w; r += w.w * (dp * dp - dn * dn);
    return r;
}

// WAVE-PRIVATE staging: wave w stages exactly its own 2-row slice
// (tile-float4 [192w, 192w+192)) of A/P/N — chunks {3w, 3w+1, 3w+2}.
// No inter-wave dependency -> no barriers in the stream loop; each wave
// free-runs on its own vmcnt pipeline.
__device__ __forceinline__ void issue_tile(int wbase, int lane,
    const float4* __restrict__ gA, const float4* __restrict__ gP,
    const float4* __restrict__ gN,
    float4* bA, float4* bP, float4* bN)
{
    #pragma unroll
    for (int j = 0; j < 3; ++j) {
        const int off = wbase + 64 * j;
        __builtin_amdgcn_global_load_lds((const AS1 void*)(gA + off + lane),
                                         (AS3 void*)(bA + off), 16, 0, 0);
        __builtin_amdgcn_global_load_lds((const AS1 void*)(gP + off + lane),
                                         (AS3 void*)(bP + off), 16, 0, 0);
        __builtin_amdgcn_global_load_lds((const AS1 void*)(gN + off + lane),
                                         (AS3 void*)(bN + off), 16, 0, 0);
    }
}

__global__ __launch_bounds__(BLOCK) void triplet_partial(
    const float4* __restrict__ A, const float4* __restrict__ P,
    const float4* __restrict__ N, const float* __restrict__ W,
    float* __restrict__ partial)
{
    __shared__ float4 sA[2][TILE_F4];
    __shared__ float4 sP[2][TILE_F4];
    __shared__ float4 sN[2][TILE_F4];
    __shared__ float wpart[BLOCK / 64];

    const int lane  = threadIdx.x & 63;
    const int wave  = threadIdx.x >> 6;
    const int bid   = blockIdx.x;
    const int wbase = 192 * wave;            // this wave's slice in the tile

    // exp(W) fragments; slice starts at an even row so slot s / lane L maps
    // to W4 index (64s + L) mod 96.
    const float4* W4 = reinterpret_cast<const float4*>(W);
    float4 w0 = W4[lane];
    float4 w1 = W4[(lane < 32) ? (64 + lane) : (lane - 32)];
    float4 w2 = W4[32 + lane];
    w0.x = expf(w0.x); w0.y = expf(w0.y); w0.z = expf(w0.z); w0.w = expf(w0.w);
    w1.x = expf(w1.x); w1.y = expf(w1.y); w1.z = expf(w1.z); w1.w = expf(w1.w);
    w2.x = expf(w2.x); w2.y = expf(w2.y); w2.z = expf(w2.z); w2.w = expf(w2.w);
    const bool lo = (lane < 32);

    float acc = 0.f;

    // Block b streams tiles {b, b+512, ...}; each wave pipelines privately.
    issue_tile(wbase, lane, A + (size_t)bid * TILE_F4, P + (size_t)bid * TILE_F4,
               N + (size_t)bid * TILE_F4, sA[0], sP[0], sN[0]);

    for (int i = 0; i < TILES_PER_BLOCK; ++i) {
        if (i + 1 < TILES_PER_BLOCK) {
            const size_t g = (size_t)(bid + NBLOCKS * (i + 1)) * TILE_F4;
            issue_tile(wbase, lane, A + g, P + g, N + g,
                       sA[(i + 1) & 1], sP[(i + 1) & 1], sN[(i + 1) & 1]);
            // wait for THIS wave's tile-i chunks; tile-(i+1)'s 9 stay in flight
            asm volatile("s_waitcnt vmcnt(9)" ::: "memory");
        } else {
            asm volatile("s_waitcnt vmcnt(0)" ::: "memory");
        }
        __builtin_amdgcn_sched_barrier(0);

        const int b = i & 1;
        const float4 a0 = sA[b][wbase + lane];
        const float4 p0 = sP[b][wbase + lane];
        const float4 n0 = sN[b][wbase + lane];
        const float4 a1 = sA[b][wbase + 64 + lane];
        const float4 p1 = sP[b][wbase + 64 + lane];
        const float4 n1 = sN[b][wbase + 64 + lane];
        const float4 a2 = sA[b][wbase + 128 + lane];
        const float4 p2 = sP[b][wbase + 128 + lane];
        const float4 n2 = sN[b][wbase + 128 + lane];

        const float v0 = wdot(w0, a0, p0, n0);
        const float v1 = wdot(w1, a1, p1, n1);
        const float v2 = wdot(w2, a2, p2, n2);

        float x0 = v0 + (lo ? v1 : 0.f);     // row 2*(4*bid_tile + wave)
        float x1 = v2 + (lo ? 0.f : v1);     // row ... + 1
        #pragma unroll
        for (int m = 1; m < 64; m <<= 1) {
            x0 += __shfl_xor(x0, m, 64);
            x1 += __shfl_xor(x1, m, 64);
        }
        acc += fmaxf(x0 + ALPHA, 0.f) + fmaxf(x1 + ALPHA, 0.f);
        // no barrier: buffer (i&1) is re-staged only by THIS wave at i+2,
        // after these ds_reads have completed (their values fed acc above).
    }

    if (lane == 0) wpart[wave] = acc;
    __syncthreads();
    if (threadIdx.x == 0)
        partial[bid] = wpart[0] + wpart[1] + wpart[2] + wpart[3];
}

__global__ __launch_bounds__(256) void triplet_finish(
    const float* __restrict__ partial, float* __restrict__ out)
{
    __shared__ float lds[256];
    float s = 0.f;
    for (int i = threadIdx.x; i < NBLOCKS; i += 256) s += partial[i];
    lds[threadIdx.x] = s;
    __syncthreads();
    for (int ofs = 128; ofs > 0; ofs >>= 1) {
        if (threadIdx.x < ofs) lds[threadIdx.x] += lds[threadIdx.x + ofs];
        __syncthreads();
    }
    if (threadIdx.x == 0) out[0] = lds[0] / (float)BATCH;
}

extern "C" void kernel_launch(void* const* d_in, const int* in_sizes, int n_in,
                              void* d_out, int out_size, void* d_ws, size_t ws_size,
                              hipStream_t stream) {
    const float4* A = (const float4*)d_in[0];
    const float4* P = (const float4*)d_in[1];
    const float4* N = (const float4*)d_in[2];
    const float*  W = (const float*)d_in[3];
    float* partial = (float*)d_ws;   // NBLOCKS floats, fully written each call
    float* out = (float*)d_out;

    triplet_partial<<<NBLOCKS, BLOCK, 0, stream>>>(A, P, N, W, partial);
    triplet_finish<<<1, 256, 0, stream>>>(partial, out);
}